// Round 2
// baseline (659.806 us; speedup 1.0000x reference)
//
#include <hip/hip_runtime.h>
#include <math.h>

#define DIM 128
#define CHUNK 8        // nodes per stream per round (8 x 512B in flight per half-wave)
#define GPB 8          // graphs per block: one graph per half-wave stream
#define NUM_GRAPHS_EXPECTED 4096

typedef float v4f __attribute__((ext_vector_type(4)));

// Kernel A: segment boundaries. seg[g] = first index i with batch[i] >= g,
// for g in [0, ng]. One coalesced pass over batch.
__global__ __launch_bounds__(256) void seg_bounds_kernel(
    const int* __restrict__ batch, int* __restrict__ seg, int n, int ng)
{
    const int i = blockIdx.x * blockDim.x + threadIdx.x;
    if (i > n) return;
    const int prev = (i == 0) ? -1 : batch[i - 1];
    const int cur  = (i == n) ? ng : batch[i];
    for (int g = prev + 1; g <= cur; ++g) seg[g] = i;
}

// Kernel B: one GRAPH per 32-lane half-wave. 256 threads = 8 half-wave
// streams = 8 graphs per block; grid = NUM_GRAPHS/8 = 512 blocks = exactly
// 2 blocks/CU, all resident from t=0. Each stream runs a ~30-round-deep
// software pipeline over its graph's contiguous node range (CHUNK=8 rows
// prefetched while the previous 8 are reduced). No LDS, no __syncthreads:
// after the online softmax the 32 lanes of a stream hold the complete
// state for their graph (l is lane-replicated, o covers 4 dims/lane).
__global__ __launch_bounds__(256, 2) void attnpool_kernel(
    const float* __restrict__ x, const float* __restrict__ q,
    const int* __restrict__ seg, float* __restrict__ out)
{
    const int tid  = threadIdx.x;
    const int wave = tid >> 6;
    const int lane = tid & 63;
    const int half = lane >> 5;   // 0 or 1
    const int hl   = lane & 31;   // lane within half
    const int sid  = wave * 2 + half;
    const int g    = blockIdx.x * GPB + sid;   // this stream's graph

    const int lo = seg[g];
    const int hi = seg[g + 1];

    // per-lane query fragment (dims hl*4 .. hl*4+3)
    const float4 qf = *(const float4*)(q + hl * 4);
    const float* xb = x + hl * 4;

    float  m = -INFINITY;
    float  l = 0.f;
    float4 o = make_float4(0.f, 0.f, 0.f, 0.f);

    // clamped row index: unconditional loads, no exec-masked divergence.
    // empty graph (hi<=lo): loop never runs; prologue reads row 0 (safe).
    const int safe_last = (hi > lo) ? (hi - 1) : 0;

    v4f cur[CHUNK];
    #pragma unroll
    for (int j = 0; j < CHUNK; ++j) {
        const int ii = (lo + j < hi) ? (lo + j) : safe_last;
        cur[j] = *(const v4f*)(xb + (size_t)ii * DIM);
    }

    for (int t = lo; t < hi; t += CHUNK) {
        // prefetch next chunk (stays in flight through the reductions)
        v4f nxt[CHUNK];
        #pragma unroll
        for (int j = 0; j < CHUNK; ++j) {
            const int ii = (t + CHUNK + j < hi) ? (t + CHUNK + j) : safe_last;
            nxt[j] = *(const v4f*)(xb + (size_t)ii * DIM);
        }

        // 8 independent dot partials
        float s[CHUNK];
        #pragma unroll
        for (int j = 0; j < CHUNK; ++j)
            s[j] = cur[j].x * qf.x + cur[j].y * qf.y + cur[j].z * qf.z + cur[j].w * qf.w;

        // 8 interleaved butterfly trees over the 32-lane half (masks <=16)
        #pragma unroll
        for (int d = 16; d >= 1; d >>= 1) {
            #pragma unroll
            for (int j = 0; j < CHUNK; ++j)
                s[j] += __shfl_xor(s[j], d);
        }

        // invalidate tail entries (uniform within the half-wave)
        #pragma unroll
        for (int j = 0; j < CHUNK; ++j)
            if (t + j >= hi) s[j] = -INFINITY;

        float smax = s[0];
        #pragma unroll
        for (int j = 1; j < CHUNK; ++j) smax = fmaxf(smax, s[j]);

        if (smax > m) {   // one rescale per round; m=-inf first time -> exp=0
            const float a = __expf(m - smax);
            l *= a;
            o.x *= a; o.y *= a; o.z *= a; o.w *= a;
            m = smax;
        }

        #pragma unroll
        for (int j = 0; j < CHUNK; ++j) {
            const float p = (t + j < hi) ? __expf(s[j] - m) : 0.f;
            l += p;
            o.x += p * cur[j].x; o.y += p * cur[j].y;
            o.z += p * cur[j].z; o.w += p * cur[j].w;
        }

        #pragma unroll
        for (int j = 0; j < CHUNK; ++j) cur[j] = nxt[j];
    }

    // direct write-out: 32 lanes x float4 = this graph's 128 outputs.
    // empty segment -> l==0 -> zeros (matches segment_sum identity).
    const float inv = (l > 0.f) ? (1.f / l) : 0.f;
    float4 r;
    r.x = o.x * inv; r.y = o.y * inv; r.z = o.z * inv; r.w = o.w * inv;
    *(float4*)(out + (size_t)g * DIM + hl * 4) = r;
}

extern "C" void kernel_launch(void* const* d_in, const int* in_sizes, int n_in,
                              void* d_out, int out_size, void* d_ws, size_t ws_size,
                              hipStream_t stream) {
    const float* x     = (const float*)d_in[0];
    const float* q     = (const float*)d_in[1];
    const int*   batch = (const int*)d_in[2];
    float*       out   = (float*)d_out;
    const int n          = in_sizes[0] / DIM;   // 1,000,000
    const int num_graphs = out_size / DIM;      // 4096

    int* seg = (int*)d_ws;                      // (num_graphs + 1) ints
    const int sb = (n + 1 + 255) / 256;
    seg_bounds_kernel<<<sb, 256, 0, stream>>>(batch, seg, n, num_graphs);
    attnpool_kernel<<<num_graphs / GPB, 256, 0, stream>>>(x, q, seg, out);
}